// Round 1
// baseline (154.909 us; speedup 1.0000x reference)
//
#include <hip/hip_runtime.h>
#include <stdint.h>

static constexpr int BLOCK = 256;
static constexpr int ITEMS = 16;
static constexpr int CHUNK = BLOCK * ITEMS;   // 4096 elements per block
static constexpr int MAXNB = 512;             // 512 * 4096 = 2097152 = N

#define GAMMA_F 0.99f
static __device__ __forceinline__ float gl_const() { return (float)(0.99 * 0.95); }

// ---------------- bool dtype runtime probe ----------------
// Returns 0 = int32, 1 = uint8/bool, 2 = float32 (0.0/1.0).
// Looks at the first 1024 bytes: for i32 0/1 data bytes (i%4)!=0 are all 0;
// for u8 Bernoulli data byte positions %4==1 are nonzero w.p. 1-2^-256;
// for f32 (1.0f = 00 00 80 3F) only positions %4 in {2,3} are nonzero.
__device__ __forceinline__ int detect_mode(const void* term, int n_elems, int* flg) {
    int t = threadIdx.x;
    if (t == 0) { flg[0] = 0; flg[1] = 0; }
    __syncthreads();
    if (t < 256) {
        const unsigned char* p = (const unsigned char*)term;
        int i0 = 4 * t;
        if (i0 + 3 < n_elems) {   // n_elems bytes exist even in the u8 case
            unsigned b1 = p[i0 + 1], b2 = p[i0 + 2], b3 = p[i0 + 3];
            if (b1) atomicOr(&flg[0], 1);
            if (b2 | b3) atomicOr(&flg[1], 1);
        }
    }
    __syncthreads();
    return flg[0] ? 1 : (flg[1] ? 2 : 0);
}

__device__ __forceinline__ int load_bool1(const void* p, long i, int mode) {
    if (mode == 1) return ((const unsigned char*)p)[i] != 0;
    if (mode == 0) return ((const int*)p)[i] != 0;
    return ((const float*)p)[i] != 0.0f;
}

__device__ __forceinline__ void load_bool16(const void* p, long base, int mode, int* f) {
    if (mode == 1) {
        uint4 q = *(const uint4*)((const unsigned char*)p + base);
        unsigned w[4] = {q.x, q.y, q.z, q.w};
#pragma unroll
        for (int j = 0; j < 16; ++j) f[j] = (int)((w[j >> 2] >> ((j & 3) * 8)) & 0xffu);
    } else if (mode == 0) {
        const int4* q = (const int4*)((const int*)p + base);
#pragma unroll
        for (int k = 0; k < 4; ++k) {
            int4 v = q[k];
            f[4*k] = v.x; f[4*k+1] = v.y; f[4*k+2] = v.z; f[4*k+3] = v.w;
        }
    } else {
        const float4* q = (const float4*)((const float*)p + base);
#pragma unroll
        for (int k = 0; k < 4; ++k) {
            float4 v = q[k];
            f[4*k] = v.x != 0.f; f[4*k+1] = v.y != 0.f; f[4*k+2] = v.z != 0.f; f[4*k+3] = v.w != 0.f;
        }
    }
}

// c[j] = not_done * gamma*lambda ; d[j] = r + gamma*not_term*nv - v
__device__ __forceinline__ void compute_cd(
    const float* __restrict__ rewards, const float* __restrict__ values,
    const float* __restrict__ next_values, const void* __restrict__ term,
    const void* __restrict__ trunc, int mode, long base, int n,
    float* c, float* d, float* v)
{
    const float GL = gl_const();
    if (base + ITEMS <= n) {
        float r[ITEMS], nv[ITEMS];
        const float4* r4 = (const float4*)(rewards + base);
        const float4* v4 = (const float4*)(values + base);
        const float4* n4 = (const float4*)(next_values + base);
#pragma unroll
        for (int k = 0; k < 4; ++k) {
            float4 a = r4[k]; r[4*k]=a.x; r[4*k+1]=a.y; r[4*k+2]=a.z; r[4*k+3]=a.w;
            float4 b = v4[k]; v[4*k]=b.x; v[4*k+1]=b.y; v[4*k+2]=b.z; v[4*k+3]=b.w;
            float4 q = n4[k]; nv[4*k]=q.x; nv[4*k+1]=q.y; nv[4*k+2]=q.z; nv[4*k+3]=q.w;
        }
        int tm[ITEMS], tr[ITEMS];
        load_bool16(term,  base, mode, tm);
        load_bool16(trunc, base, mode, tr);
#pragma unroll
        for (int j = 0; j < ITEMS; ++j) {
            float nt = tm[j] ? 0.f : 1.f;
            float nd = (tm[j] | tr[j]) ? 0.f : 1.f;
            d[j] = r[j] + GAMMA_F * nt * nv[j] - v[j];
            c[j] = nd * GL;
        }
    } else {
#pragma unroll
        for (int j = 0; j < ITEMS; ++j) {
            long i = base + j;
            if (i < (long)n) {
                int tm = load_bool1(term, i, mode);
                int tr = load_bool1(trunc, i, mode);
                float nt = tm ? 0.f : 1.f;
                float nd = (tm | tr) ? 0.f : 1.f;
                v[j] = values[i];
                d[j] = rewards[i] + GAMMA_F * nt * next_values[i] - v[j];
                c[j] = nd * GL;
            } else { c[j] = 1.f; d[j] = 0.f; v[j] = 0.f; }
        }
    }
}

// ---------------- K1: per-block affine aggregate ----------------
__global__ __launch_bounds__(BLOCK) void k1_agg(
    const float* __restrict__ rewards, const float* __restrict__ values,
    const float* __restrict__ next_values, const void* __restrict__ term,
    const void* __restrict__ trunc, float2* __restrict__ blockAgg, int n)
{
    __shared__ int flg[2];
    __shared__ float sA[BLOCK], sB[BLOCK];
    int mode = detect_mode(term, n, flg);
    int t = threadIdx.x;
    long base = (long)blockIdx.x * CHUNK + (long)t * ITEMS;
    float c[ITEMS], d[ITEMS], v[ITEMS];
    compute_cd(rewards, values, next_values, term, trunc, mode, base, n, c, d, v);
    float a = 1.f, b = 0.f;
#pragma unroll
    for (int j = ITEMS - 1; j >= 0; --j) { b = c[j]*b + d[j]; a = c[j]*a; }
    sA[t] = a; sB[t] = b;
    __syncthreads();
    // suffix-inclusive Hillis-Steele: H_t = F_t ∘ F_{t+1} ∘ ... ∘ F_{255}
    for (int dd = 1; dd < BLOCK; dd <<= 1) {
        float ra = 1.f, rb = 0.f;
        if (t + dd < BLOCK) { ra = sA[t + dd]; rb = sB[t + dd]; }
        __syncthreads();
        b = a * rb + b;    // uses old a
        a = a * ra;
        sA[t] = a; sB[t] = b;
        __syncthreads();
    }
    if (t == 0) blockAgg[blockIdx.x] = make_float2(a, b);
}

// ---------------- K2: suffix scan of block aggregates ----------------
__global__ __launch_bounds__(MAXNB) void k2_scan(
    const float2* __restrict__ blockAgg, float* __restrict__ S,
    double* __restrict__ sums, int nb)
{
    __shared__ float sA[MAXNB], sB[MAXNB];
    int t = threadIdx.x;
    float a = 1.f, b = 0.f;
    if (t < nb) { float2 f = blockAgg[t]; a = f.x; b = f.y; }
    sA[t] = a; sB[t] = b;
    __syncthreads();
    for (int dd = 1; dd < MAXNB; dd <<= 1) {
        float ra = 1.f, rb = 0.f;
        if (t + dd < MAXNB) { ra = sA[t + dd]; rb = sB[t + dd]; }
        __syncthreads();
        b = a * rb + b;
        a = a * ra;
        sA[t] = a; sB[t] = b;
        __syncthreads();
    }
    if (t < nb) S[t] = (t + 1 < nb) ? sB[t + 1] : 0.f;  // exclusive-from-right applied to 0
    if (t == 0) { sums[0] = 0.0; sums[1] = 0.0; }
}

// ---------------- K3: replay -> adv, lambda_returns; accumulate sums ----------------
__global__ __launch_bounds__(BLOCK) void k3_adv(
    const float* __restrict__ rewards, const float* __restrict__ values,
    const float* __restrict__ next_values, const void* __restrict__ term,
    const void* __restrict__ trunc, const float* __restrict__ S,
    float* __restrict__ out, double* __restrict__ sums, int n)
{
    __shared__ int flg[2];
    __shared__ float sA[BLOCK], sB[BLOCK];
    int mode = detect_mode(term, n, flg);
    int t = threadIdx.x;
    long base = (long)blockIdx.x * CHUNK + (long)t * ITEMS;
    float c[ITEMS], d[ITEMS], v[ITEMS];
    compute_cd(rewards, values, next_values, term, trunc, mode, base, n, c, d, v);
    float a = 1.f, b = 0.f;
#pragma unroll
    for (int j = ITEMS - 1; j >= 0; --j) { b = c[j]*b + d[j]; a = c[j]*a; }
    sA[t] = a; sB[t] = b;
    __syncthreads();
    for (int dd = 1; dd < BLOCK; dd <<= 1) {
        float ra = 1.f, rb = 0.f;
        if (t + dd < BLOCK) { ra = sA[t + dd]; rb = sB[t + dd]; }
        __syncthreads();
        b = a * rb + b;
        a = a * ra;
        sA[t] = a; sB[t] = b;
        __syncthreads();
    }
    // E_t = H_{t+1} (identity for t=255); thread start value = E_t(S_block)
    float ea = 1.f, eb = 0.f;
    if (t + 1 < BLOCK) { ea = sA[t + 1]; eb = sB[t + 1]; }
    float x = ea * S[blockIdx.x] + eb;
    float s = 0.f, s2 = 0.f;
    float adv[ITEMS];
#pragma unroll
    for (int j = ITEMS - 1; j >= 0; --j) {
        x = c[j] * x + d[j];
        adv[j] = x;
        if (base + j < (long)n) { s += x; s2 += x * x; }
    }
    if (base + ITEMS <= n) {
#pragma unroll
        for (int j = 0; j < ITEMS; ++j) {
            long o = 3 * (base + j);
            out[o]     = adv[j];          // unnormalized adv (normalized in K4)
            out[o + 1] = adv[j] + v[j];   // lambda_returns (final)
        }
    } else {
        for (int j = 0; j < ITEMS; ++j) {
            long i = base + j;
            if (i < (long)n) { long o = 3*i; out[o] = adv[j]; out[o+1] = adv[j] + v[j]; }
        }
    }
    __syncthreads();   // done reading sA/sB for scan purposes
    sA[t] = s; sB[t] = s2;
    __syncthreads();
    for (int dd = BLOCK / 2; dd > 0; dd >>= 1) {
        if (t < dd) { sA[t] += sA[t + dd]; sB[t] += sB[t + dd]; }
        __syncthreads();
    }
    if (t == 0) {
        atomicAdd(&sums[0], (double)sA[0]);
        atomicAdd(&sums[1], (double)sB[0]);
    }
}

// ---------------- K4: normalize + actor loss (in-place float4 RMW) ----------------
__global__ __launch_bounds__(BLOCK) void k4_final(
    const float* __restrict__ lp, const float* __restrict__ olp,
    const double* __restrict__ sums, float* __restrict__ out, int n)
{
    long e = ((long)blockIdx.x * blockDim.x + threadIdx.x) * 4;
    if (e >= n) return;
    double sum = sums[0], sumsq = sums[1];
    float mean = (float)(sum / (double)n);
    double var = (sumsq - sum * sum / (double)n) / (double)(n - 1);
    if (var < 0.0) var = 0.0;
    float inv = 1.0f / ((float)sqrt(var) + 1e-9f);
    if (e + 4 <= n) {
        float4 l  = *(const float4*)(lp + e);
        float4 o  = *(const float4*)(olp + e);
        float4 t0 = *(float4*)(out + 3 * e);
        float4 t1 = *(float4*)(out + 3 * e + 4);
        float4 t2 = *(float4*)(out + 3 * e + 8);
        float advv[4] = {t0.x, t0.w, t1.z, t2.y};
        float lv[4]   = {l.x, l.y, l.z, l.w};
        float ov[4]   = {o.x, o.y, o.z, o.w};
        float an[4], ls[4];
#pragma unroll
        for (int j = 0; j < 4; ++j) {
            an[j] = (advv[j] - mean) * inv;
            float ratio = expf(lv[j] - ov[j]);
            float cl = fminf(fmaxf(ratio, 0.8f), 1.2f);
            ls[j] = -fminf(ratio * an[j], cl * an[j]);
        }
        t0.x = an[0]; t0.z = ls[0]; t0.w = an[1];
        t1.y = ls[1]; t1.z = an[2];
        t2.x = ls[2]; t2.y = an[3]; t2.w = ls[3];
        *(float4*)(out + 3 * e)     = t0;
        *(float4*)(out + 3 * e + 4) = t1;
        *(float4*)(out + 3 * e + 8) = t2;
    } else {
        for (long i = e; i < (long)n; ++i) {
            float advv = out[3 * i];
            float an = (advv - mean) * inv;
            float ratio = expf(lp[i] - olp[i]);
            float cl = fminf(fmaxf(ratio, 0.8f), 1.2f);
            out[3 * i]     = an;
            out[3 * i + 2] = -fminf(ratio * an, cl * an);
        }
    }
}

extern "C" void kernel_launch(void* const* d_in, const int* in_sizes, int n_in,
                              void* d_out, int out_size, void* d_ws, size_t ws_size,
                              hipStream_t stream) {
    const float* rewards     = (const float*)d_in[0];
    const float* values      = (const float*)d_in[1];
    const float* next_values = (const float*)d_in[2];
    const float* lp          = (const float*)d_in[3];
    const float* olp         = (const float*)d_in[4];
    const void*  term        = d_in[5];
    const void*  trunc       = d_in[6];
    float* out = (float*)d_out;
    int n = in_sizes[0];

    double* sums     = (double*)d_ws;                                   // 16 B
    float2* blockAgg = (float2*)((char*)d_ws + 64);                     // 4 KB
    float*  S        = (float*)((char*)d_ws + 64 + MAXNB * sizeof(float2));

    int nb = (n + CHUNK - 1) / CHUNK;   // 512 for N=2^21 (must be <= MAXNB)

    k1_agg <<<nb, BLOCK, 0, stream>>>(rewards, values, next_values, term, trunc, blockAgg, n);
    k2_scan<<<1, MAXNB, 0, stream>>>(blockAgg, S, sums, nb);
    k3_adv <<<nb, BLOCK, 0, stream>>>(rewards, values, next_values, term, trunc, S, out, sums, n);
    int n4blocks = (int)(((long)n / 4 + BLOCK - 1) / BLOCK);
    k4_final<<<n4blocks, BLOCK, 0, stream>>>(lp, olp, sums, out, n);
}